// Round 3
// baseline (312.868 us; speedup 1.0000x reference)
//
#include <hip/hip_runtime.h>
#include <math.h>

#define NPG    23
#define HID    48
#define HEADS  4
#define C1     192   // HEADS*HID
#define NFEAT  11
#define GG     1024  // B*T graphs
#define GRUH   64
#define FRAME  96
#define TT     16
#define BB     64

#define HSTR   196   // padded row stride for h/h1 (floats)
#define GSTR   52    // padded row stride for g

// LDS layout (floats), total 9456 = 37824 B -> 4 blocks/CU
#define OFF_X    0      // x tile (253); later als2(23)+ald2(23); later frame(96)
#define OFF_ALS  256    // 92  [hh*23+n]
#define OFF_ALD  348    // 92
#define OFF_H    440    // 23*196 (reused as g(23*52) + h2(23*48) later)
#define OFF_H1   4948   // 23*196
#define LDSF     9456

__device__ __forceinline__ float elu_(float v) {
    return (v > 0.f) ? v : (__expf(v) - 1.f);
}

// ---------------------------------------------------------------------------
// Kernel 1: per-graph GAT1(4h) -> ELU -> GAT2 -> ELU -> pool -> gi0 row.
// 192 threads/block, 1024 blocks (4 blocks/CU). All GEMM phases register-
// tiled so each weight element is loaded O(1) times per block.
// ---------------------------------------------------------------------------
__global__ __launch_bounds__(192, 3) void gat_fused(
    const float* __restrict__ x,      // NTOT x 11
    const float* __restrict__ W1,     // 11 x 192
    const float* __restrict__ as1,    // 192
    const float* __restrict__ ad1,    // 192
    const float* __restrict__ b1,     // 192
    const float* __restrict__ W2,     // 192 x 48
    const float* __restrict__ as2,    // 48
    const float* __restrict__ ad2,    // 48
    const float* __restrict__ b2,     // 48
    const float* __restrict__ Wih0,   // 192 x 96
    const float* __restrict__ bih0,   // 192
    float* __restrict__ gi0)          // G x 192
{
    __shared__ float S[LDSF];
    float* s_x    = S + OFF_X;
    float* s_als  = S + OFF_ALS;
    float* s_ald  = S + OFF_ALD;
    float* s_h    = S + OFF_H;
    float* s_h1   = S + OFF_H1;
    float* s_g    = S + OFF_H;              // overlays h (dead after E')
    float* s_h2   = S + OFF_H + NPG * GSTR; // after g
    float* s_als2 = S + OFF_X;              // overlays x (dead after B)
    float* s_ald2 = S + OFF_X + NPG;
    float* s_frame= S + OFF_X;              // overlays als2/ald2 (dead after H')

    const int g   = blockIdx.x;
    const int tid = threadIdx.x;

    // ---- load x tile ----
    for (int i = tid; i < NPG * NFEAT; i += 192) s_x[i] = x[g * NPG * NFEAT + i];
    __syncthreads();

    // ---- B: h = x @ W1, n-tile 6 (W1 read 4x/block) ----
    {
        const int c4 = tid >> 2, nh = tid & 3;  // c4 0..47, nh 0..3
        float4 acc[6];
        #pragma unroll
        for (int nn = 0; nn < 6; nn++) acc[nn] = make_float4(0.f, 0.f, 0.f, 0.f);
        #pragma unroll
        for (int k = 0; k < NFEAT; k++) {
            const float4 w = *(const float4*)(W1 + k * C1 + 4 * c4);
            #pragma unroll
            for (int nn = 0; nn < 6; nn++) {
                int n = nh * 6 + nn; n = (n < NPG) ? n : NPG - 1;
                const float xv = s_x[n * NFEAT + k];
                acc[nn].x += xv * w.x; acc[nn].y += xv * w.y;
                acc[nn].z += xv * w.z; acc[nn].w += xv * w.w;
            }
        }
        #pragma unroll
        for (int nn = 0; nn < 6; nn++) {
            const int n = nh * 6 + nn;
            if (n < NPG) *(float4*)(s_h + n * HSTR + 4 * c4) = acc[nn];
        }
    }
    __syncthreads();

    // ---- L1: attention logits als/ald (184 threads, direct writes) ----
    if (tid < 184) {
        const int which = tid / 92, r = tid % 92, hh = r / NPG, n = r % NPG;
        const float* av = (which ? ad1 : as1) + hh * HID;
        const float* hp = s_h + n * HSTR + hh * HID;
        float s = 0.f;
        #pragma unroll
        for (int k4 = 0; k4 < 12; k4++) {
            const float4 h4 = *(const float4*)(hp + 4 * k4);
            const float4 a4 = *(const float4*)(av + 4 * k4);
            s += h4.x * a4.x + h4.y * a4.y + h4.z * a4.z + h4.w * a4.w;
        }
        if (which) s_ald[hh * NPG + n] = s; else s_als[hh * NPG + n] = s;
    }
    __syncthreads();

    // ---- E': softmax1 (on-the-fly, j-tile 2) + aggregate + b1 + ELU -> h1 ----
    if (tid < 96) {
        const int q = tid & 1, hh = (tid >> 1) & 3, jp = tid >> 3;  // jp 0..11
        const int j0 = 2 * jp, j1 = 2 * jp + 1;
        const bool has1 = (j1 < NPG);
        const int cb = hh * HID + q * 24;
        const float* alsb = s_als + hh * NPG;
        const float ald0 = s_ald[hh * NPG + j0];
        const float ald1 = has1 ? s_ald[hh * NPG + j1] : 0.f;
        float m0 = -1e30f, m1 = -1e30f;
        #pragma unroll
        for (int i = 0; i < NPG; i++) {
            const float ai = alsb[i];
            float e0 = ai + ald0; e0 = (e0 > 0.f) ? e0 : 0.2f * e0;
            float e1 = ai + ald1; e1 = (e1 > 0.f) ? e1 : 0.2f * e1;
            m0 = fmaxf(m0, e0); m1 = fmaxf(m1, e1);
        }
        float4 acc0[6], acc1[6];
        #pragma unroll
        for (int c = 0; c < 6; c++) {
            acc0[c] = make_float4(0.f, 0.f, 0.f, 0.f);
            acc1[c] = make_float4(0.f, 0.f, 0.f, 0.f);
        }
        float ss0 = 0.f, ss1 = 0.f;
        #pragma unroll
        for (int i = 0; i < NPG; i++) {
            const float ai = alsb[i];
            float e0 = ai + ald0; e0 = (e0 > 0.f) ? e0 : 0.2f * e0;
            float e1 = ai + ald1; e1 = (e1 > 0.f) ? e1 : 0.2f * e1;
            const float p0 = __expf(e0 - m0); ss0 += p0;
            const float p1 = __expf(e1 - m1); ss1 += p1;
            const float* hp = s_h + i * HSTR + cb;
            #pragma unroll
            for (int c = 0; c < 6; c++) {
                const float4 hv = *(const float4*)(hp + 4 * c);
                acc0[c].x += p0 * hv.x; acc0[c].y += p0 * hv.y;
                acc0[c].z += p0 * hv.z; acc0[c].w += p0 * hv.w;
                acc1[c].x += p1 * hv.x; acc1[c].y += p1 * hv.y;
                acc1[c].z += p1 * hv.z; acc1[c].w += p1 * hv.w;
            }
        }
        const float inv0 = 1.f / (ss0 + 1e-16f);
        const float inv1 = 1.f / (ss1 + 1e-16f);
        #pragma unroll
        for (int c = 0; c < 6; c++) {
            const float4 bb = *(const float4*)(b1 + cb + 4 * c);
            float4 v;
            v.x = elu_(acc0[c].x * inv0 + bb.x);
            v.y = elu_(acc0[c].y * inv0 + bb.y);
            v.z = elu_(acc0[c].z * inv0 + bb.z);
            v.w = elu_(acc0[c].w * inv0 + bb.w);
            *(float4*)(s_h1 + j0 * HSTR + cb + 4 * c) = v;
            if (has1) {
                v.x = elu_(acc1[c].x * inv1 + bb.x);
                v.y = elu_(acc1[c].y * inv1 + bb.y);
                v.z = elu_(acc1[c].z * inv1 + bb.z);
                v.w = elu_(acc1[c].w * inv1 + bb.w);
                *(float4*)(s_h1 + j1 * HSTR + cb + 4 * c) = v;
            }
        }
    }
    __syncthreads();

    // ---- F: g = h1 @ W2, k-split 8 x n-tile 12 (W2 read 2x/block),
    //         shfl-butterfly reduce over the 8 k-groups ----
    {
        const int kc = tid & 7, ng = (tid >> 3) & 1, c4 = tid >> 4;  // c4 0..11
        const int nbase = ng * 12;
        float4 acc[12];
        #pragma unroll
        for (int nn = 0; nn < 12; nn++) acc[nn] = make_float4(0.f, 0.f, 0.f, 0.f);
        #pragma unroll
        for (int k4 = 0; k4 < 6; k4++) {
            int k4s = k4 + 3 * ng; if (k4s >= 6) k4s -= 6;  // ng-stagger (banks)
            const int kk = kc * 6 + k4s;                    // float4 index 0..47
            const float* w2p = W2 + (4 * kk) * HID + 4 * c4;
            const float4 r0 = *(const float4*)(w2p);
            const float4 r1 = *(const float4*)(w2p + HID);
            const float4 r2 = *(const float4*)(w2p + 2 * HID);
            const float4 r3 = *(const float4*)(w2p + 3 * HID);
            const float* h1p = s_h1 + 4 * kk;
            #pragma unroll
            for (int nn = 0; nn < 12; nn++) {
                int n = nbase + nn; n = (n < NPG) ? n : NPG - 1;
                const float4 hv = *(const float4*)(h1p + n * HSTR);
                acc[nn].x += hv.x*r0.x + hv.y*r1.x + hv.z*r2.x + hv.w*r3.x;
                acc[nn].y += hv.x*r0.y + hv.y*r1.y + hv.z*r2.y + hv.w*r3.y;
                acc[nn].z += hv.x*r0.z + hv.y*r1.z + hv.z*r2.z + hv.w*r3.z;
                acc[nn].w += hv.x*r0.w + hv.y*r1.w + hv.z*r2.w + hv.w*r3.w;
            }
        }
        #pragma unroll
        for (int nn = 0; nn < 12; nn++) {
            float4 a = acc[nn];
            a.x += __shfl_xor(a.x, 1); a.x += __shfl_xor(a.x, 2); a.x += __shfl_xor(a.x, 4);
            a.y += __shfl_xor(a.y, 1); a.y += __shfl_xor(a.y, 2); a.y += __shfl_xor(a.y, 4);
            a.z += __shfl_xor(a.z, 1); a.z += __shfl_xor(a.z, 2); a.z += __shfl_xor(a.z, 4);
            a.w += __shfl_xor(a.w, 1); a.w += __shfl_xor(a.w, 2); a.w += __shfl_xor(a.w, 4);
            const int n = nbase + nn;
            if (kc == 0 && n < NPG) *(float4*)(s_g + n * GSTR + 4 * c4) = a;
        }
    }
    __syncthreads();

    // ---- L2: layer-2 logits (46 threads, direct writes) ----
    if (tid < 46) {
        const int which = tid / NPG, n = tid % NPG;
        const float* av = which ? ad2 : as2;
        const float* gp = s_g + n * GSTR;
        float s = 0.f;
        #pragma unroll
        for (int k4 = 0; k4 < 12; k4++) {
            const float4 g4 = *(const float4*)(gp + 4 * k4);
            const float4 a4 = *(const float4*)(av + 4 * k4);
            s += g4.x * a4.x + g4.y * a4.y + g4.z * a4.z + g4.w * a4.w;
        }
        if (which) s_ald2[n] = s; else s_als2[n] = s;
    }
    __syncthreads();

    // ---- H': softmax2 (j-tile 2) + aggregate + b2 + ELU -> h2 ----
    if (tid < 48) {
        const int q = tid & 3, jp = tid >> 2;
        const int j0 = 2 * jp, j1 = 2 * jp + 1;
        const bool has1 = (j1 < NPG);
        const int cb = q * 12;
        const float ald0 = s_ald2[j0];
        const float ald1 = has1 ? s_ald2[j1] : 0.f;
        float m0 = -1e30f, m1 = -1e30f;
        #pragma unroll
        for (int i = 0; i < NPG; i++) {
            const float ai = s_als2[i];
            float e0 = ai + ald0; e0 = (e0 > 0.f) ? e0 : 0.2f * e0;
            float e1 = ai + ald1; e1 = (e1 > 0.f) ? e1 : 0.2f * e1;
            m0 = fmaxf(m0, e0); m1 = fmaxf(m1, e1);
        }
        float4 acc0[3], acc1[3];
        #pragma unroll
        for (int c = 0; c < 3; c++) {
            acc0[c] = make_float4(0.f, 0.f, 0.f, 0.f);
            acc1[c] = make_float4(0.f, 0.f, 0.f, 0.f);
        }
        float ss0 = 0.f, ss1 = 0.f;
        #pragma unroll
        for (int i = 0; i < NPG; i++) {
            const float ai = s_als2[i];
            float e0 = ai + ald0; e0 = (e0 > 0.f) ? e0 : 0.2f * e0;
            float e1 = ai + ald1; e1 = (e1 > 0.f) ? e1 : 0.2f * e1;
            const float p0 = __expf(e0 - m0); ss0 += p0;
            const float p1 = __expf(e1 - m1); ss1 += p1;
            const float* gp = s_g + i * GSTR + cb;
            #pragma unroll
            for (int c = 0; c < 3; c++) {
                const float4 gv = *(const float4*)(gp + 4 * c);
                acc0[c].x += p0 * gv.x; acc0[c].y += p0 * gv.y;
                acc0[c].z += p0 * gv.z; acc0[c].w += p0 * gv.w;
                acc1[c].x += p1 * gv.x; acc1[c].y += p1 * gv.y;
                acc1[c].z += p1 * gv.z; acc1[c].w += p1 * gv.w;
            }
        }
        const float inv0 = 1.f / (ss0 + 1e-16f);
        const float inv1 = 1.f / (ss1 + 1e-16f);
        #pragma unroll
        for (int c = 0; c < 3; c++) {
            const float4 bb = *(const float4*)(b2 + cb + 4 * c);
            float4 v;
            v.x = elu_(acc0[c].x * inv0 + bb.x);
            v.y = elu_(acc0[c].y * inv0 + bb.y);
            v.z = elu_(acc0[c].z * inv0 + bb.z);
            v.w = elu_(acc0[c].w * inv0 + bb.w);
            *(float4*)(s_h2 + j0 * HID + cb + 4 * c) = v;
            if (has1) {
                v.x = elu_(acc1[c].x * inv1 + bb.x);
                v.y = elu_(acc1[c].y * inv1 + bb.y);
                v.z = elu_(acc1[c].z * inv1 + bb.z);
                v.w = elu_(acc1[c].w * inv1 + bb.w);
                *(float4*)(s_h2 + j1 * HID + cb + 4 * c) = v;
            }
        }
    }
    __syncthreads();

    // ---- pool -> s_frame (LDS) ----
    if (tid < HID) {
        float sm = 0.f, mx = -1e30f;
        #pragma unroll
        for (int j = 0; j < NPG; j++) {
            const float v = s_h2[j * HID + tid];
            sm += v; mx = fmaxf(mx, v);
        }
        s_frame[tid]       = sm * (1.0f / NPG);
        s_frame[HID + tid] = mx;
    }
    __syncthreads();

    // ---- GI0: gi0 row = frame @ Wih0^T + bih0 (moved off the serial GRU) ----
    {
        float s = bih0[tid];
        const float4* wr = (const float4*)(Wih0 + tid * FRAME);
        const float4* fr = (const float4*)s_frame;
        #pragma unroll
        for (int k4 = 0; k4 < FRAME / 4; k4++) {
            const float4 w = wr[k4];
            const float4 f = fr[k4];
            s += w.x * f.x + w.y * f.y + w.z * f.z + w.w * f.w;
        }
        gi0[g * C1 + tid] = s;
    }
}

// ---------------------------------------------------------------------------
// Kernel 2: 2-layer GRU (T=16) + MLP head. 192 thr/block, 64 blocks.
// Software-pipelined: layer-1 runs one step behind layer-0, so each timestep
// is ONE dot-phase (3 dot64s/thread, weights register-resident) + ONE update
// phase = 2 barriers (was 4).
// ---------------------------------------------------------------------------
__global__ __launch_bounds__(192) void gru_head(
    const float* __restrict__ gi0g,   // (B*T) x 192 (bih0 already added)
    const float* __restrict__ Whh0,   // 192 x 64
    const float* __restrict__ bhh0,
    const float* __restrict__ Wih1,   // 192 x 64
    const float* __restrict__ bih1,
    const float* __restrict__ Whh1,   // 192 x 64
    const float* __restrict__ bhh1,
    const float* __restrict__ Wh1,    // 64 x 32
    const float* __restrict__ bh1,
    const float* __restrict__ Wh2,    // 32 x 1
    const float* __restrict__ bh2,
    float* __restrict__ out)          // 64
{
    __shared__ float s_gi0[TT * C1];
    __shared__ float s_h0[GRUH], s_h1[GRUH];
    __shared__ float s_gh0[C1], s_gi1[C1], s_gh1[C1];
    __shared__ float s_t1[32];

    const int b = blockIdx.x, tid = threadIdx.x;

    {   // load this sequence's gi0 (16 x 192), coalesced float4
        const float4* src = (const float4*)(gi0g + b * TT * C1);
        float4* dst = (float4*)s_gi0;
        #pragma unroll
        for (int i = 0; i < 4; i++) dst[tid + 192 * i] = src[tid + 192 * i];
    }
    if (tid < GRUH) { s_h0[tid] = 0.f; s_h1[tid] = 0.f; }

    // register-resident recurrent weight rows (3 x 64 floats / thread)
    float w0[64], w1[64], w2[64];
    {
        const float4* p0 = (const float4*)(Whh0 + tid * 64);
        const float4* p1 = (const float4*)(Wih1 + tid * 64);
        const float4* p2 = (const float4*)(Whh1 + tid * 64);
        #pragma unroll
        for (int k4 = 0; k4 < 16; k4++) {
            const float4 v0 = p0[k4];
            w0[4*k4] = v0.x; w0[4*k4+1] = v0.y; w0[4*k4+2] = v0.z; w0[4*k4+3] = v0.w;
            const float4 v1 = p1[k4];
            w1[4*k4] = v1.x; w1[4*k4+1] = v1.y; w1[4*k4+2] = v1.z; w1[4*k4+3] = v1.w;
            const float4 v2 = p2[k4];
            w2[4*k4] = v2.x; w2[4*k4+1] = v2.y; w2[4*k4+2] = v2.z; w2[4*k4+3] = v2.w;
        }
    }
    const float bh0r = bhh0[tid], bi1r = bih1[tid], bh1r = bhh1[tid];
    __syncthreads();

    for (int it = 0; it <= TT; it++) {
        // P1: s0 = w0·h0[it-1], s1 = w1·h0[it-1], s2 = w2·h1[it-2]
        {
            float s0 = bh0r, s1 = bi1r, s2 = bh1r;
            const float4* h0v = (const float4*)s_h0;
            const float4* h1v = (const float4*)s_h1;
            #pragma unroll
            for (int k4 = 0; k4 < 16; k4++) {
                const float4 a = h0v[k4];
                const float4 c = h1v[k4];
                s0 += w0[4*k4]*a.x + w0[4*k4+1]*a.y + w0[4*k4+2]*a.z + w0[4*k4+3]*a.w;
                s1 += w1[4*k4]*a.x + w1[4*k4+1]*a.y + w1[4*k4+2]*a.z + w1[4*k4+3]*a.w;
                s2 += w2[4*k4]*c.x + w2[4*k4+1]*c.y + w2[4*k4+2]*c.z + w2[4*k4+3]*c.w;
            }
            s_gh0[tid] = s0; s_gi1[tid] = s1; s_gh1[tid] = s2;
        }
        __syncthreads();
        // P2: update h0[it] (lanes 0..63) and h1[it-1] (lanes 64..127)
        if (tid < GRUH) {
            if (it < TT) {
                const float ir = s_gi0[it*C1 + tid];
                const float iz = s_gi0[it*C1 + 64 + tid];
                const float in_ = s_gi0[it*C1 + 128 + tid];
                const float hr = s_gh0[tid], hz = s_gh0[64 + tid], hn = s_gh0[128 + tid];
                const float r = 1.f / (1.f + __expf(-(ir + hr)));
                const float z = 1.f / (1.f + __expf(-(iz + hz)));
                const float nx = in_ + r * hn;
                const float e2 = __expf(2.f * nx);
                const float n = (e2 - 1.f) / (e2 + 1.f);
                s_h0[tid] = (1.f - z) * n + z * s_h0[tid];
            }
        } else if (tid < 2 * GRUH) {
            if (it >= 1) {
                const int c = tid - GRUH;
                const float ir = s_gi1[c], iz = s_gi1[64 + c], in_ = s_gi1[128 + c];
                const float hr = s_gh1[c], hz = s_gh1[64 + c], hn = s_gh1[128 + c];
                const float r = 1.f / (1.f + __expf(-(ir + hr)));
                const float z = 1.f / (1.f + __expf(-(iz + hz)));
                const float nx = in_ + r * hn;
                const float e2 = __expf(2.f * nx);
                const float n = (e2 - 1.f) / (e2 + 1.f);
                s_h1[c] = (1.f - z) * n + z * s_h1[c];
            }
        }
        __syncthreads();
    }

    // ---- head: relu(h1[15] @ Wh1 + bh1) @ Wh2 + bh2 ----
    if (tid < 32) {
        float s = bh1[tid];
        #pragma unroll
        for (int k = 0; k < GRUH; k++) s += s_h1[k] * Wh1[k * 32 + tid];
        s_t1[tid] = fmaxf(s, 0.f);
    }
    __syncthreads();
    if (tid == 0) {
        float s = bh2[0];
        #pragma unroll
        for (int k = 0; k < 32; k++) s += s_t1[k] * Wh2[k];
        out[b] = s;
    }
}

extern "C" void kernel_launch(void* const* d_in, const int* in_sizes, int n_in,
                              void* d_out, int out_size, void* d_ws, size_t ws_size,
                              hipStream_t stream) {
    const float* x    = (const float*)d_in[0];
    // d_in[1] = edge_index, d_in[2] = batch : fixed dense structure -> unused
    const float* W1   = (const float*)d_in[3];
    const float* as1  = (const float*)d_in[4];
    const float* ad1  = (const float*)d_in[5];
    const float* b1   = (const float*)d_in[6];
    const float* W2   = (const float*)d_in[7];
    const float* as2  = (const float*)d_in[8];
    const float* ad2  = (const float*)d_in[9];
    const float* b2   = (const float*)d_in[10];
    const float* Wih0 = (const float*)d_in[11];
    const float* Whh0 = (const float*)d_in[12];
    const float* bih0 = (const float*)d_in[13];
    const float* bhh0 = (const float*)d_in[14];
    const float* Wih1 = (const float*)d_in[15];
    const float* Whh1 = (const float*)d_in[16];
    const float* bih1 = (const float*)d_in[17];
    const float* bhh1 = (const float*)d_in[18];
    const float* Wh1  = (const float*)d_in[19];
    const float* bh1  = (const float*)d_in[20];
    const float* Wh2  = (const float*)d_in[21];
    const float* bh2  = (const float*)d_in[22];

    float* out  = (float*)d_out;
    float* gi0  = (float*)d_ws;   // G x 192 fp32 = 786 KB

    hipLaunchKernelGGL(gat_fused, dim3(GG), dim3(192), 0, stream,
                       x, W1, as1, ad1, b1, W2, as2, ad2, b2, Wih0, bih0, gi0);
    hipLaunchKernelGGL(gru_head, dim3(BB), dim3(192), 0, stream,
                       gi0, Whh0, bhh0, Wih1, bih1, Whh1, bhh1,
                       Wh1, bh1, Wh2, bh2, out);
}

// Round 4
// 61.492 us; speedup vs baseline: 5.0880x; 5.0880x over previous
//
#include <hip/hip_runtime.h>
#include <math.h>

#define NPG    23
#define HID    48
#define HEADS  4
#define C1     192   // HEADS*HID
#define NFEAT  11
#define GG     1024  // B*T graphs
#define GRUH   64
#define FRAME  96
#define TT     16
#define BB     64

#define HSTR   196   // padded row stride for h/h1 (floats)
#define GSTR   52    // padded row stride for g

// LDS layout (floats), total 9456 = 37824 B -> 4 blocks/CU
// OFF_X region is reused: x(253) -> als2(23)+ald2(23) -> frame(96)
// OFF_H region is reused: h(23*196) -> gA(23*52) + gB(23*52) + h2(23*48)
#define OFF_X    0
#define OFF_ALS  256
#define OFF_ALD  348
#define OFF_H    440
#define OFF_H1   4948
#define LDSF     9456

__device__ __forceinline__ float elu_(float v) {
    return (v > 0.f) ? v : (__expf(v) - 1.f);
}

// ---------------------------------------------------------------------------
// Kernel 1: per-graph GAT1(4h)->ELU->GAT2->ELU->pool->gi0. 256 thr/block,
// 1024 blocks (4/CU). Register tiles kept SMALL (<=20 regs) to avoid the
// round-3 scratch spill; W2 L1 traffic cut 4x via k-split-2 x n-tile-4.
// ---------------------------------------------------------------------------
__global__ __launch_bounds__(256, 4) void gat_fused(
    const float* __restrict__ x,      // NTOT x 11
    const float* __restrict__ W1,     // 11 x 192
    const float* __restrict__ as1,    // 192
    const float* __restrict__ ad1,    // 192
    const float* __restrict__ b1,     // 192
    const float* __restrict__ W2,     // 192 x 48
    const float* __restrict__ as2,    // 48
    const float* __restrict__ ad2,    // 48
    const float* __restrict__ b2,     // 48
    const float* __restrict__ Wih0,   // 192 x 96
    const float* __restrict__ bih0,   // 192
    float* __restrict__ gi0)          // G x 192
{
    __shared__ float S[LDSF];
    float* s_x    = S + OFF_X;
    float* s_als  = S + OFF_ALS;
    float* s_ald  = S + OFF_ALD;
    float* s_h    = S + OFF_H;
    float* s_h1   = S + OFF_H1;
    float* s_gA   = S + OFF_H;               // overlays h (dead after E')
    float* s_gB   = S + OFF_H + NPG * GSTR;  // k-split partial
    float* s_h2   = S + OFF_H + 2 * NPG * GSTR;
    float* s_als2 = S + OFF_X;               // overlays x (dead after B)
    float* s_ald2 = S + OFF_X + NPG;
    float* s_frame= S + OFF_X;               // overlays als2/ald2 (dead after H')

    const int g   = blockIdx.x;
    const int tid = threadIdx.x;

    // ---- load x tile ----
    for (int i = tid; i < NPG * NFEAT; i += 256) s_x[i] = x[g * NPG * NFEAT + i];
    __syncthreads();

    // ---- B: h = x @ W1, n-tile 5 (one W1 strip per thread) ----
    if (tid < 240) {
        const int c4 = tid % 48, ng = tid / 48;  // ng 0..4
        float4 acc[5];
        #pragma unroll
        for (int nn = 0; nn < 5; nn++) acc[nn] = make_float4(0.f, 0.f, 0.f, 0.f);
        #pragma unroll
        for (int k = 0; k < NFEAT; k++) {
            const float4 w = *(const float4*)(W1 + k * C1 + 4 * c4);
            #pragma unroll
            for (int nn = 0; nn < 5; nn++) {
                int n = ng * 5 + nn; n = (n < NPG) ? n : NPG - 1;
                const float xv = s_x[n * NFEAT + k];
                acc[nn].x += xv * w.x; acc[nn].y += xv * w.y;
                acc[nn].z += xv * w.z; acc[nn].w += xv * w.w;
            }
        }
        #pragma unroll
        for (int nn = 0; nn < 5; nn++) {
            const int n = ng * 5 + nn;
            if (n < NPG) *(float4*)(s_h + n * HSTR + 4 * c4) = acc[nn];
        }
    }
    __syncthreads();

    // ---- L1: attention logits als/ald (184 threads, direct writes) ----
    if (tid < 184) {
        const int which = tid / 92, r = tid % 92, hh = r / NPG, n = r % NPG;
        const float* av = (which ? ad1 : as1) + hh * HID;
        const float* hp = s_h + n * HSTR + hh * HID;
        float s = 0.f;
        #pragma unroll
        for (int k4 = 0; k4 < 12; k4++) {
            const float4 h4 = *(const float4*)(hp + 4 * k4);
            const float4 a4 = *(const float4*)(av + 4 * k4);
            s += h4.x * a4.x + h4.y * a4.y + h4.z * a4.z + h4.w * a4.w;
        }
        if (which) s_ald[hh * NPG + n] = s; else s_als[hh * NPG + n] = s;
    }
    __syncthreads();

    // ---- E': softmax1 (alpha in regs, round-2 proven) + agg + b1 + ELU ----
    if (tid < 184) {
        const int j = tid >> 3, sub = tid & 7;
        const int hh = sub >> 1, half = sub & 1;
        const float ald_j = s_ald[hh * NPG + j];
        float a[NPG];
        float m = -1e30f;
        #pragma unroll
        for (int i = 0; i < NPG; i++) {
            float e = s_als[hh * NPG + i] + ald_j;
            e = (e > 0.f) ? e : 0.2f * e;
            a[i] = e;
            m = fmaxf(m, e);
        }
        float ssum = 0.f;
        #pragma unroll
        for (int i = 0; i < NPG; i++) {
            const float w = __expf(a[i] - m);
            a[i] = w;
            ssum += w;
        }
        const float inv = 1.f / (ssum + 1e-16f);
        const int cb = hh * HID + half * 24;
        #pragma unroll
        for (int c4 = 0; c4 < 6; c4++) {
            float4 acc = make_float4(0.f, 0.f, 0.f, 0.f);
            #pragma unroll
            for (int i = 0; i < NPG; i++) {
                const float4 hv = *(const float4*)(s_h + i * HSTR + cb + 4 * c4);
                acc.x += a[i] * hv.x; acc.y += a[i] * hv.y;
                acc.z += a[i] * hv.z; acc.w += a[i] * hv.w;
            }
            const float4 bb = *(const float4*)(b1 + cb + 4 * c4);
            float4 v;
            v.x = elu_(acc.x * inv + bb.x);
            v.y = elu_(acc.y * inv + bb.y);
            v.z = elu_(acc.z * inv + bb.z);
            v.w = elu_(acc.w * inv + bb.w);
            *(float4*)(s_h1 + j * HSTR + cb + 4 * c4) = v;
        }
    }
    __syncthreads();

    // ---- F: g = h1 @ W2, k-split 2 x n-tile 4 (W2 read 6x not 23x) ----
    if (tid < 144) {
        const int c4 = tid % 12, ng = (tid / 12) % 6, kc = tid / 72;
        float4 acc[4];
        #pragma unroll
        for (int nn = 0; nn < 4; nn++) acc[nn] = make_float4(0.f, 0.f, 0.f, 0.f);
        const int kbase = kc * 24;  // float4 k-index; 24 per split
        #pragma unroll 4
        for (int k4 = 0; k4 < 24; k4++) {
            const int kk = kbase + k4;
            const float* w2p = W2 + (4 * kk) * HID + 4 * c4;
            const float4 r0 = *(const float4*)(w2p);
            const float4 r1 = *(const float4*)(w2p + HID);
            const float4 r2 = *(const float4*)(w2p + 2 * HID);
            const float4 r3 = *(const float4*)(w2p + 3 * HID);
            #pragma unroll
            for (int nn = 0; nn < 4; nn++) {
                int n = ng * 4 + nn; n = (n < NPG) ? n : NPG - 1;
                const float4 hv = *(const float4*)(s_h1 + n * HSTR + 4 * kk);
                acc[nn].x += hv.x*r0.x + hv.y*r1.x + hv.z*r2.x + hv.w*r3.x;
                acc[nn].y += hv.x*r0.y + hv.y*r1.y + hv.z*r2.y + hv.w*r3.y;
                acc[nn].z += hv.x*r0.z + hv.y*r1.z + hv.z*r2.z + hv.w*r3.z;
                acc[nn].w += hv.x*r0.w + hv.y*r1.w + hv.z*r2.w + hv.w*r3.w;
            }
        }
        float* dstb = kc ? s_gB : s_gA;
        #pragma unroll
        for (int nn = 0; nn < 4; nn++) {
            const int n = ng * 4 + nn;
            if (n < NPG) *(float4*)(dstb + n * GSTR + 4 * c4) = acc[nn];
        }
    }
    __syncthreads();

    // ---- combine k-split partials into s_gA ----
    for (int task = tid; task < NPG * 12; task += 256) {
        const int n = task / 12, c4 = task % 12;
        const float4 a = *(const float4*)(s_gA + n * GSTR + 4 * c4);
        const float4 b = *(const float4*)(s_gB + n * GSTR + 4 * c4);
        *(float4*)(s_gA + n * GSTR + 4 * c4) =
            make_float4(a.x + b.x, a.y + b.y, a.z + b.z, a.w + b.w);
    }
    __syncthreads();

    // ---- L2: layer-2 logits (46 threads, direct writes) ----
    if (tid < 46) {
        const int which = tid / NPG, n = tid % NPG;
        const float* av = which ? ad2 : as2;
        const float* gp = s_gA + n * GSTR;
        float s = 0.f;
        #pragma unroll
        for (int k4 = 0; k4 < 12; k4++) {
            const float4 g4 = *(const float4*)(gp + 4 * k4);
            const float4 a4 = *(const float4*)(av + 4 * k4);
            s += g4.x * a4.x + g4.y * a4.y + g4.z * a4.z + g4.w * a4.w;
        }
        if (which) s_ald2[n] = s; else s_als2[n] = s;
    }
    __syncthreads();

    // ---- H': softmax2 (regs) + aggregate + b2 + ELU -> h2 ----
    if (tid < 92) {
        const int j = tid >> 2, q = tid & 3;
        const float ald_j = s_ald2[j];
        float a[NPG];
        float m = -1e30f;
        #pragma unroll
        for (int i = 0; i < NPG; i++) {
            float e = s_als2[i] + ald_j;
            e = (e > 0.f) ? e : 0.2f * e;
            a[i] = e;
            m = fmaxf(m, e);
        }
        float ssum = 0.f;
        #pragma unroll
        for (int i = 0; i < NPG; i++) {
            const float w = __expf(a[i] - m);
            a[i] = w;
            ssum += w;
        }
        const float inv = 1.f / (ssum + 1e-16f);
        #pragma unroll
        for (int c4 = 0; c4 < 3; c4++) {
            const int cb = q * 12 + 4 * c4;
            float4 acc = make_float4(0.f, 0.f, 0.f, 0.f);
            #pragma unroll
            for (int i = 0; i < NPG; i++) {
                const float4 gv = *(const float4*)(s_gA + i * GSTR + cb);
                acc.x += a[i] * gv.x; acc.y += a[i] * gv.y;
                acc.z += a[i] * gv.z; acc.w += a[i] * gv.w;
            }
            const float4 bb = *(const float4*)(b2 + cb);
            float4 v;
            v.x = elu_(acc.x * inv + bb.x);
            v.y = elu_(acc.y * inv + bb.y);
            v.z = elu_(acc.z * inv + bb.z);
            v.w = elu_(acc.w * inv + bb.w);
            *(float4*)(s_h2 + j * HID + cb) = v;
        }
    }
    __syncthreads();

    // ---- pool -> s_frame (LDS) ----
    if (tid < HID) {
        float sm = 0.f, mx = -1e30f;
        #pragma unroll
        for (int j = 0; j < NPG; j++) {
            const float v = s_h2[j * HID + tid];
            sm += v; mx = fmaxf(mx, v);
        }
        s_frame[tid]       = sm * (1.0f / NPG);
        s_frame[HID + tid] = mx;
    }
    __syncthreads();

    // ---- GI0: gi0 row = frame @ Wih0^T + bih0 ----
    if (tid < C1) {
        float s = bih0[tid];
        const float4* wr = (const float4*)(Wih0 + tid * FRAME);
        const float4* fr = (const float4*)s_frame;
        #pragma unroll
        for (int k4 = 0; k4 < FRAME / 4; k4++) {
            const float4 w = wr[k4];
            const float4 f = fr[k4];
            s += w.x * f.x + w.y * f.y + w.z * f.z + w.w * f.w;
        }
        gi0[g * C1 + tid] = s;
    }
}

// ---------------------------------------------------------------------------
// Kernel 2: 2-layer GRU (T=16) + MLP head. 192 thr/block, 64 blocks.
// Software-pipelined: layer-1 one step behind layer-0 -> 2 barriers/step.
// (round-3 version, measured ~12us, correct)
// ---------------------------------------------------------------------------
__global__ __launch_bounds__(192) void gru_head(
    const float* __restrict__ gi0g,   // (B*T) x 192 (bih0 already added)
    const float* __restrict__ Whh0,   // 192 x 64
    const float* __restrict__ bhh0,
    const float* __restrict__ Wih1,   // 192 x 64
    const float* __restrict__ bih1,
    const float* __restrict__ Whh1,   // 192 x 64
    const float* __restrict__ bhh1,
    const float* __restrict__ Wh1,    // 64 x 32
    const float* __restrict__ bh1,
    const float* __restrict__ Wh2,    // 32 x 1
    const float* __restrict__ bh2,
    float* __restrict__ out)          // 64
{
    __shared__ float s_gi0[TT * C1];
    __shared__ float s_h0[GRUH], s_h1[GRUH];
    __shared__ float s_gh0[C1], s_gi1[C1], s_gh1[C1];
    __shared__ float s_t1[32];

    const int b = blockIdx.x, tid = threadIdx.x;

    {   // load this sequence's gi0 (16 x 192), coalesced float4
        const float4* src = (const float4*)(gi0g + b * TT * C1);
        float4* dst = (float4*)s_gi0;
        #pragma unroll
        for (int i = 0; i < 4; i++) dst[tid + 192 * i] = src[tid + 192 * i];
    }
    if (tid < GRUH) { s_h0[tid] = 0.f; s_h1[tid] = 0.f; }

    // register-resident recurrent weight rows (3 x 64 floats / thread)
    float w0[64], w1[64], w2[64];
    {
        const float4* p0 = (const float4*)(Whh0 + tid * 64);
        const float4* p1 = (const float4*)(Wih1 + tid * 64);
        const float4* p2 = (const float4*)(Whh1 + tid * 64);
        #pragma unroll
        for (int k4 = 0; k4 < 16; k4++) {
            const float4 v0 = p0[k4];
            w0[4*k4] = v0.x; w0[4*k4+1] = v0.y; w0[4*k4+2] = v0.z; w0[4*k4+3] = v0.w;
            const float4 v1 = p1[k4];
            w1[4*k4] = v1.x; w1[4*k4+1] = v1.y; w1[4*k4+2] = v1.z; w1[4*k4+3] = v1.w;
            const float4 v2 = p2[k4];
            w2[4*k4] = v2.x; w2[4*k4+1] = v2.y; w2[4*k4+2] = v2.z; w2[4*k4+3] = v2.w;
        }
    }
    const float bh0r = bhh0[tid], bi1r = bih1[tid], bh1r = bhh1[tid];
    __syncthreads();

    for (int it = 0; it <= TT; it++) {
        // P1: s0 = w0·h0[it-1], s1 = w1·h0[it-1], s2 = w2·h1[it-2]
        {
            float s0 = bh0r, s1 = bi1r, s2 = bh1r;
            const float4* h0v = (const float4*)s_h0;
            const float4* h1v = (const float4*)s_h1;
            #pragma unroll
            for (int k4 = 0; k4 < 16; k4++) {
                const float4 a = h0v[k4];
                const float4 c = h1v[k4];
                s0 += w0[4*k4]*a.x + w0[4*k4+1]*a.y + w0[4*k4+2]*a.z + w0[4*k4+3]*a.w;
                s1 += w1[4*k4]*a.x + w1[4*k4+1]*a.y + w1[4*k4+2]*a.z + w1[4*k4+3]*a.w;
                s2 += w2[4*k4]*c.x + w2[4*k4+1]*c.y + w2[4*k4+2]*c.z + w2[4*k4+3]*c.w;
            }
            s_gh0[tid] = s0; s_gi1[tid] = s1; s_gh1[tid] = s2;
        }
        __syncthreads();
        // P2: update h0[it] (lanes 0..63) and h1[it-1] (lanes 64..127)
        if (tid < GRUH) {
            if (it < TT) {
                const float ir = s_gi0[it*C1 + tid];
                const float iz = s_gi0[it*C1 + 64 + tid];
                const float in_ = s_gi0[it*C1 + 128 + tid];
                const float hr = s_gh0[tid], hz = s_gh0[64 + tid], hn = s_gh0[128 + tid];
                const float r = 1.f / (1.f + __expf(-(ir + hr)));
                const float z = 1.f / (1.f + __expf(-(iz + hz)));
                const float nx = in_ + r * hn;
                const float e2 = __expf(2.f * nx);
                const float n = (e2 - 1.f) / (e2 + 1.f);
                s_h0[tid] = (1.f - z) * n + z * s_h0[tid];
            }
        } else if (tid < 2 * GRUH) {
            if (it >= 1) {
                const int c = tid - GRUH;
                const float ir = s_gi1[c], iz = s_gi1[64 + c], in_ = s_gi1[128 + c];
                const float hr = s_gh1[c], hz = s_gh1[64 + c], hn = s_gh1[128 + c];
                const float r = 1.f / (1.f + __expf(-(ir + hr)));
                const float z = 1.f / (1.f + __expf(-(iz + hz)));
                const float nx = in_ + r * hn;
                const float e2 = __expf(2.f * nx);
                const float n = (e2 - 1.f) / (e2 + 1.f);
                s_h1[c] = (1.f - z) * n + z * s_h1[c];
            }
        }
        __syncthreads();
    }

    // ---- head: relu(h1[15] @ Wh1 + bh1) @ Wh2 + bh2 ----
    if (tid < 32) {
        float s = bh1[tid];
        #pragma unroll
        for (int k = 0; k < GRUH; k++) s += s_h1[k] * Wh1[k * 32 + tid];
        s_t1[tid] = fmaxf(s, 0.f);
    }
    __syncthreads();
    if (tid == 0) {
        float s = bh2[0];
        #pragma unroll
        for (int k = 0; k < 32; k++) s += s_t1[k] * Wh2[k];
        out[b] = s;
    }
}

extern "C" void kernel_launch(void* const* d_in, const int* in_sizes, int n_in,
                              void* d_out, int out_size, void* d_ws, size_t ws_size,
                              hipStream_t stream) {
    const float* x    = (const float*)d_in[0];
    // d_in[1] = edge_index, d_in[2] = batch : fixed dense structure -> unused
    const float* W1   = (const float*)d_in[3];
    const float* as1  = (const float*)d_in[4];
    const float* ad1  = (const float*)d_in[5];
    const float* b1   = (const float*)d_in[6];
    const float* W2   = (const float*)d_in[7];
    const float* as2  = (const float*)d_in[8];
    const float* ad2  = (const float*)d_in[9];
    const float* b2   = (const float*)d_in[10];
    const float* Wih0 = (const float*)d_in[11];
    const float* Whh0 = (const float*)d_in[12];
    const float* bih0 = (const float*)d_in[13];
    const float* bhh0 = (const float*)d_in[14];
    const float* Wih1 = (const float*)d_in[15];
    const float* Whh1 = (const float*)d_in[16];
    const float* bih1 = (const float*)d_in[17];
    const float* bhh1 = (const float*)d_in[18];
    const float* Wh1  = (const float*)d_in[19];
    const float* bh1  = (const float*)d_in[20];
    const float* Wh2  = (const float*)d_in[21];
    const float* bh2  = (const float*)d_in[22];

    float* out  = (float*)d_out;
    float* gi0  = (float*)d_ws;   // G x 192 fp32 = 786 KB

    hipLaunchKernelGGL(gat_fused, dim3(GG), dim3(256), 0, stream,
                       x, W1, as1, ad1, b1, W2, as2, ad2, b2, Wih0, bih0, gi0);
    hipLaunchKernelGGL(gru_head, dim3(BB), dim3(192), 0, stream,
                       gi0, Whh0, bhh0, Wih1, bih1, Whh1, bhh1,
                       Wh1, bh1, Wh2, bh2, out);
}